// Round 12
// baseline (601.856 us; speedup 1.0000x reference)
//
#include <hip/hip_runtime.h>

#define Adim 4096
#define HD 128
#define TSTEPS 30
#define NROWS 24576
#define RBLK 32
#define NBLKS 768           // NROWS / RBLK
#define DT_C 0.2f
#define SQDT_C 0.44721359549995794f
#define LN_EPS 1e-5f

#define PI_OFF   2949120    // 6*4096*30*4
#define MASK_OFF 2973696    // PI_OFF + 24576

typedef unsigned short u16;
typedef __bf16 bf16x8 __attribute__((ext_vector_type(8)));
typedef float f32x4 __attribute__((ext_vector_type(4)));

__device__ __forceinline__ u16 f2bf(float x){
    unsigned u = __builtin_bit_cast(unsigned, x);
    u = (u + 0x7fffu + ((u >> 16) & 1u)) >> 16;
    return (u16)u;
}
__device__ __forceinline__ float bf2f(unsigned h){
    unsigned u = (h & 0xffffu) << 16;
    return __builtin_bit_cast(float, u);
}
__device__ __forceinline__ unsigned pack2(float a, float b){
    unsigned r;
    asm("v_cvt_pk_bf16_f32 %0, %1, %2" : "=v"(r) : "v"(a), "v"(b));
    return r;
}
__device__ __forceinline__ float tanh_f(float x){
    return 1.0f - 2.0f / (1.0f + __expf(2.0f * x));
}
__device__ __forceinline__ float sigm_f(float x){
    return 1.0f / (1.0f + __expf(-x));
}
#define SWZ(r,k) ((k) ^ (((r)&7)<<3))
#define MFMA(A,B,C) __builtin_amdgcn_mfma_f32_16x16x32_bf16(A, B, C, 0, 0, 0)

// ---- per-wave weight fragments: 16 output channels per wave ----
__device__ __forceinline__ void loadW(const u16* __restrict__ img, int lane, int wid,
                                      bf16x8 W[4]) {
    const int c = wid*16 + (lane & 15);
    const int kq = lane >> 4;
#pragma unroll
    for (int kk = 0; kk < 4; ++kk)
        W[kk] = *reinterpret_cast<const bf16x8*>(img + c*HD + SWZ(c, kk*32 + kq*8));
}

// ---- GEMMs (swapped): D[c][r] = sum_k W[c][k] act[r][k]; 32 rows = 2 tiles ----
__device__ __forceinline__ void gemm1(const u16* __restrict__ act, const bf16x8 (&W)[4],
                                      int lane, f32x4 acc[2]) {
    const int rl = lane & 15, kq = lane >> 4;
    __builtin_amdgcn_s_setprio(1);
#pragma unroll
    for (int tr = 0; tr < 2; ++tr) {
        const int r = tr*16 + rl;
        const u16* arow = act + r*HD;
        f32x4 a = {0.f,0.f,0.f,0.f};
#pragma unroll
        for (int kk = 0; kk < 4; ++kk) {
            bf16x8 bf = *reinterpret_cast<const bf16x8*>(arow + SWZ(r, kk*32 + kq*8));
            a = MFMA(W[kk], bf, a);
        }
        acc[tr] = a;
    }
    __builtin_amdgcn_s_setprio(0);
}
__device__ __forceinline__ void gemm2(const u16* __restrict__ act,
                                      const bf16x8 (&Wx)[4], const bf16x8 (&Wy)[4],
                                      int lane, f32x4 accX[2], f32x4 accY[2]) {
    const int rl = lane & 15, kq = lane >> 4;
    __builtin_amdgcn_s_setprio(1);
#pragma unroll
    for (int tr = 0; tr < 2; ++tr) {
        const int r = tr*16 + rl;
        const u16* arow = act + r*HD;
        f32x4 ax = {0.f,0.f,0.f,0.f}, ay = {0.f,0.f,0.f,0.f};
#pragma unroll
        for (int kk = 0; kk < 4; ++kk) {
            bf16x8 bf = *reinterpret_cast<const bf16x8*>(arow + SWZ(r, kk*32 + kq*8));
            ax = MFMA(Wx[kk], bf, ax);
            ay = MFMA(Wy[kk], bf, ay);
        }
        accX[tr] = ax; accY[tr] = ay;
    }
    __builtin_amdgcn_s_setprio(0);
}
__device__ __forceinline__ void gemm4(const u16* __restrict__ act,
                                      const bf16x8 (&W1)[4], const bf16x8 (&W2)[4],
                                      const bf16x8 (&W3)[4], const bf16x8 (&W4)[4],
                                      int lane, f32x4 a1[2], f32x4 a2[2],
                                      f32x4 a3[2], f32x4 a4[2]) {
    const int rl = lane & 15, kq = lane >> 4;
    __builtin_amdgcn_s_setprio(1);
#pragma unroll
    for (int tr = 0; tr < 2; ++tr) {
        const int r = tr*16 + rl;
        const u16* arow = act + r*HD;
        f32x4 x1={0.f,0.f,0.f,0.f}, x2={0.f,0.f,0.f,0.f};
        f32x4 x3={0.f,0.f,0.f,0.f}, x4={0.f,0.f,0.f,0.f};
#pragma unroll
        for (int kk = 0; kk < 4; ++kk) {
            bf16x8 bf = *reinterpret_cast<const bf16x8*>(arow + SWZ(r, kk*32 + kq*8));
            x1 = MFMA(W1[kk], bf, x1);
            x2 = MFMA(W2[kk], bf, x2);
            x3 = MFMA(W3[kk], bf, x3);
            x4 = MFMA(W4[kk], bf, x4);
        }
        a1[tr]=x1; a2[tr]=x2; a3[tr]=x3; a4[tr]=x4;
    }
    __builtin_amdgcn_s_setprio(0);
}

// ---- epilogues: lane holds 2 row-tiles, 4 consecutive channels ----
__device__ __forceinline__ void epiT(const f32x4 acc[2], const float4& b,
                                     u16* dst, int lane, int wid) {
    const int c0 = wid*16 + ((lane>>4)<<2);
    const int rl = lane & 15;
#pragma unroll
    for (int tr = 0; tr < 2; ++tr) {
        int r = tr*16 + rl;
        float v0 = tanh_f(acc[tr][0] + b.x);
        float v1 = tanh_f(acc[tr][1] + b.y);
        float v2 = tanh_f(acc[tr][2] + b.z);
        float v3 = tanh_f(acc[tr][3] + b.w);
        uint2 pk = { pack2(v0, v1), pack2(v2, v3) };
        *reinterpret_cast<uint2*>(dst + r*HD + SWZ(r, c0)) = pk;
    }
}
__device__ __forceinline__ void epiN(const f32x4 acc[2], const float4& b,
                                     u16* dst, int lane, int wid) {
    const int c0 = wid*16 + ((lane>>4)<<2);
    const int rl = lane & 15;
#pragma unroll
    for (int tr = 0; tr < 2; ++tr) {
        int r = tr*16 + rl;
        uint2 pk = { pack2(acc[tr][0]+b.x, acc[tr][1]+b.y),
                     pack2(acc[tr][2]+b.z, acc[tr][3]+b.w) };
        *reinterpret_cast<uint2*>(dst + r*HD + SWZ(r, c0)) = pk;
    }
}
__device__ __forceinline__ void epiF(const f32x4 acc[2], const float* __restrict__ bias,
                                     float* dst, int lane, int wid) {
    const int c0 = wid*16 + ((lane>>4)<<2);
    const int rl = lane & 15;
    float4 b4 = *reinterpret_cast<const float4*>(bias + c0);
#pragma unroll
    for (int tr = 0; tr < 2; ++tr) {
        int r = tr*16 + rl;
        float4 v = { acc[tr][0]+b4.x, acc[tr][1]+b4.y, acc[tr][2]+b4.z, acc[tr][3]+b4.w };
        *reinterpret_cast<float4*>(dst + r*HD + c0) = v;
    }
}

// ---- prologue GEMM over Xc (lda=256) ----
__device__ __forceinline__ void gemmX(const u16* __restrict__ Xc, int kBase,
                                      const u16* __restrict__ img,
                                      int lane, int wid, f32x4 acc[2], bool init) {
    bf16x8 W[4]; loadW(img, lane, wid, W);
    const int rl = lane & 15, kq = lane >> 4;
#pragma unroll
    for (int tr = 0; tr < 2; ++tr) {
        const int r = tr*16 + rl;
        const u16* arow = Xc + r*256;
        f32x4 a = init ? f32x4{0.f,0.f,0.f,0.f} : acc[tr];
#pragma unroll
        for (int kk = 0; kk < 4; ++kk) {
            bf16x8 bf = *reinterpret_cast<const bf16x8*>(arow + SWZ(r, kBase + kk*32 + kq*8));
            a = MFMA(W[kk], bf, a);
        }
        acc[tr] = a;
    }
}

// ---- LN + relu + 2-wide head; 8 lanes/row; params float4 swizzled in LDS ----
__device__ __forceinline__ void head_ln(const u16* __restrict__ src,
                                        const float4* __restrict__ pp4,
                                        float b20, float b21, int elu, int off, int idx,
                                        float* __restrict__ dstStep)
{
    int row = idx >> 3, sub = idx & 7;
    int c0 = sub * 16;
    uint4 p0 = *reinterpret_cast<const uint4*>(src + row*HD + SWZ(row, c0));
    uint4 p1 = *reinterpret_cast<const uint4*>(src + row*HD + SWZ(row, c0+8));
    float v[16];
    v[0]=bf2f(p0.x); v[1]=bf2f(p0.x>>16); v[2]=bf2f(p0.y); v[3]=bf2f(p0.y>>16);
    v[4]=bf2f(p0.z); v[5]=bf2f(p0.z>>16); v[6]=bf2f(p0.w); v[7]=bf2f(p0.w>>16);
    v[8]=bf2f(p1.x); v[9]=bf2f(p1.x>>16); v[10]=bf2f(p1.y); v[11]=bf2f(p1.y>>16);
    v[12]=bf2f(p1.z); v[13]=bf2f(p1.z>>16); v[14]=bf2f(p1.w); v[15]=bf2f(p1.w>>16);
    float s = 0.f, sq = 0.f;
#pragma unroll
    for (int i = 0; i < 16; ++i){ s += v[i]; sq += v[i]*v[i]; }
    s += __shfl_xor(s,1); sq += __shfl_xor(sq,1);
    s += __shfl_xor(s,2); sq += __shfl_xor(sq,2);
    s += __shfl_xor(s,4); sq += __shfl_xor(sq,4);
    float mu = s * (1.f/128.f);
    float rstd = rsqrtf(sq*(1.f/128.f) - mu*mu + LN_EPS);
    float a0 = 0.f, a1 = 0.f;
#pragma unroll
    for (int i = 0; i < 16; ++i){
        float4 p = pp4[(c0 + i) ^ sub];
        float h = (v[i]-mu)*rstd*p.x + p.y;
        h = fmaxf(h, 0.f);
        a0 += h * p.z; a1 += h * p.w;
    }
    a0 += __shfl_xor(a0,1); a1 += __shfl_xor(a1,1);
    a0 += __shfl_xor(a0,2); a1 += __shfl_xor(a1,2);
    a0 += __shfl_xor(a0,4); a1 += __shfl_xor(a1,4);
    if (sub == 0){
        a0 += b20; a1 += b21;
        if (elu){
            a0 = (a0 > 0.f ? a0 : __expf(a0)-1.f) + 1.001f;
            a1 = (a1 > 0.f ? a1 : __expf(a1)-1.f) + 1.001f;
        }
        *reinterpret_cast<float2*>(dstStep + row*4 + off) = make_float2(a0, a1);
    }
}

// ---------- weight image prep: f32 -> bf16, transposed, swizzled ----------
__global__ void prep_w(const float* __restrict__ fw1, const float* __restrict__ fw2,
                       const float* __restrict__ fw3, const float* __restrict__ gw1,
                       const float* __restrict__ gw2, const float* __restrict__ dw1,
                       const float* __restrict__ sw1, const float* __restrict__ aw,
                       const float* __restrict__ pw1, u16* __restrict__ ws)
{
    int img = blockIdx.y;
    int idx = blockIdx.x * 256 + threadIdx.x;   // 0..16383
    int k = idx >> 7, j = idx & 127;
    const float* W = fw1; int sr = k;
    switch (img) {
        case 0: W = fw1; break;  case 1: W = fw2; break;  case 2: W = fw3; break;
        case 3: W = gw1; break;  case 4: W = gw2; break;
        case 5: W = dw1; break;  case 6: W = sw1; break;
        case 7: W = aw;  break;  case 8: W = aw;  sr = k + 128; break;
        case 9: W = pw1; break;  case 10: W = pw1; sr = k + 128; break;
    }
    ws[(size_t)img*16384 + j*128 + SWZ(j, k)] = f2bf(W[(size_t)sr*128 + j]);
}

// ---------- final output reorder: ws [blk][tt][row][4] -> loc_out [gr][tt][4] ----------
__global__ void reorder_out(const float* __restrict__ wsOut, float* __restrict__ outp)
{
    __shared__ float tile[3840];
    int b = blockIdx.x;
    const float* src = wsOut + (size_t)b*3840;
#pragma unroll
    for (int j = 0; j < 15; ++j) {
        int idx = j*256 + threadIdx.x;        // tt*128 + row*4 + c
        int tt = idx >> 7, rc = idx & 127;
        int row = rc >> 2, c = idx & 3;
        tile[row*120 + tt*4 + c] = src[idx];
    }
    __syncthreads();
    float* dst = outp + (size_t)b*3840;
#pragma unroll
    for (int j = 0; j < 15; ++j) {
        int idx = j*256 + threadIdx.x;
        dst[idx] = tile[idx];
    }
}

// ---------- the fused persistent kernel ----------
__global__ __launch_bounds__(512, 2) void sde_fused(
    const float* __restrict__ lE, const float* __restrict__ gE,
    const float* __restrict__ noise,
    const float* __restrict__ aggr_b, const float* __restrict__ aggr_g, const float* __restrict__ aggr_be,
    const float* __restrict__ fw1, const float* __restrict__ fb1,
    const float* __restrict__ fb2, const float* __restrict__ fb3,
    const float* __restrict__ gw1, const float* __restrict__ gb1,
    const float* __restrict__ gb2, const float* __restrict__ gw3, const float* __restrict__ gb3,
    const float* __restrict__ db1, const float* __restrict__ dg, const float* __restrict__ dbe,
    const float* __restrict__ dw2, const float* __restrict__ db2,
    const float* __restrict__ sb1, const float* __restrict__ sg, const float* __restrict__ sbe,
    const float* __restrict__ sw2, const float* __restrict__ sb2,
    const float* __restrict__ pb1, const float* __restrict__ pg, const float* __restrict__ pbe,
    const float* __restrict__ pw2, const float* __restrict__ pb2,
    const unsigned char* __restrict__ pmask,
    const u16* __restrict__ wimg,
    float* __restrict__ wsOut,
    float* __restrict__ outp)
{
    // LDS (54272 B): Sb@0 Ab@8K Bb@16K Cb@24K Db@32K Eb@40K (8K each)
    //   gpart[32][8] @48K (1K) | ppd @49K (2K) | pps @51K (2K)
    // prologue aliases: Xc (16K) over Db+Eb; preLN f32 (16K) over Ab+Bb
    __shared__ __align__(16) unsigned char SMEM[54272];
    u16*  Sb    = (u16*)SMEM;
    u16*  Ab    = (u16*)(SMEM + 8192);
    u16*  Bb    = (u16*)(SMEM + 16384);
    u16*  Cb    = (u16*)(SMEM + 24576);
    u16*  Db    = (u16*)(SMEM + 32768);
    u16*  Eb    = (u16*)(SMEM + 40960);
    float* gpart = (float*)(SMEM + 49152);     // [32][8]
    float4* ppd = (float4*)(SMEM + 50176);
    float4* pps = (float4*)(SMEM + 52224);
    u16*  Xc    = (u16*)(SMEM + 32768);
    float* preLN = (float*)(SMEM + 8192);

    const int tid  = threadIdx.x;
    const int lane = tid & 63;
    const int wid  = tid >> 6;
    const int bid  = blockIdx.x;
    const int r0   = bid * RBLK;
    const int rl   = lane & 15;
    const int c0e  = wid*16 + ((lane>>4)<<2);

    // -------- stage params + Xc --------
    if (tid < 128) {
        int cs = tid ^ ((tid >> 4) & 7);
        ppd[cs] = make_float4(dg[tid], dbe[tid], dw2[2*tid], dw2[2*tid+1]);
        pps[cs] = make_float4(sg[tid], sbe[tid], sw2[2*tid], sw2[2*tid+1]);
    }
#pragma unroll
    for (int i = 0; i < 2; ++i) {
        int gidx = i*512 + tid;
        int r = gidx >> 5;
        int k = (gidx & 31) * 8;
        int gr = r0 + r;
        const float* src = (k < HD) ? (gE + (size_t)gr*HD + k)
                                    : (lE + (size_t)(gr & (Adim-1))*HD + (k - HD));
        float4 v0 = reinterpret_cast<const float4*>(src)[0];
        float4 v1 = reinterpret_cast<const float4*>(src)[1];
        uint4 pk = { pack2(v0.x, v0.y), pack2(v0.z, v0.w),
                     pack2(v1.x, v1.y), pack2(v1.z, v1.w) };
        *reinterpret_cast<uint4*>(Xc + r*256 + SWZ(r, k)) = pk;
    }
    __syncthreads();

    f32x4 acc[2];

    // -------- pi head --------
    gemmX(Xc, 0,   wimg + 10*16384, lane, wid, acc, true);
    gemmX(Xc, 128, wimg + 9*16384,  lane, wid, acc, false);
    epiF(acc, pb1, preLN, lane, wid);
    __syncthreads();
    {
        int row = tid >> 4, sub = tid & 15;
        int c0 = sub * 8;
        const float* yr = preLN + row*HD + c0;
        float v[8]; float s = 0.f, sq = 0.f;
#pragma unroll
        for (int i = 0; i < 8; ++i){ float x = yr[i]; v[i] = x; s += x; sq += x*x; }
        s += __shfl_xor(s,1); sq += __shfl_xor(sq,1);
        s += __shfl_xor(s,2); sq += __shfl_xor(sq,2);
        s += __shfl_xor(s,4); sq += __shfl_xor(sq,4);
        s += __shfl_xor(s,8); sq += __shfl_xor(sq,8);
        float mu = s*(1.f/128.f);
        float rstd = rsqrtf(sq*(1.f/128.f) - mu*mu + LN_EPS);
        float a0 = 0.f;
#pragma unroll
        for (int i = 0; i < 8; ++i){
            int cc = c0 + i;
            float h = (v[i]-mu)*rstd*pg[cc] + pbe[cc];
            a0 += fmaxf(h, 0.f) * pw2[cc];
        }
        a0 += __shfl_xor(a0,1); a0 += __shfl_xor(a0,2);
        a0 += __shfl_xor(a0,4); a0 += __shfl_xor(a0,8);
        if (sub == 0) {
            int gr = r0 + row;
            outp[PI_OFF + (size_t)(gr & (Adim-1))*6 + (gr >> 12)] = a0 + pb2[0];
        }
    }
    if (tid < RBLK) {
        int gr = r0 + tid;
        if (gr < Adim) {
            const unsigned char* pm = pmask + (size_t)gr*50 + 20;
            float* o = outp + MASK_OFF + (size_t)gr*TSTEPS;
#pragma unroll
            for (int i = 0; i < TSTEPS; ++i) o[i] = pm[i] ? 0.f : 1.f;
        }
    }
    __syncthreads();

    // -------- aggr head -> h0 --------
    gemmX(Xc, 0,   wimg + 7*16384, lane, wid, acc, true);
    gemmX(Xc, 128, wimg + 8*16384, lane, wid, acc, false);
    __syncthreads();
    epiF(acc, aggr_b, preLN, lane, wid);
    __syncthreads();
    {
        int row = tid >> 4, sub = tid & 15;
        int c0 = sub * 8;
        float* yr = preLN + row*HD + c0;
        float v[8]; float s = 0.f, sq = 0.f;
#pragma unroll
        for (int i = 0; i < 8; ++i){ float x = yr[i]; v[i] = x; s += x; sq += x*x; }
        s += __shfl_xor(s,1); sq += __shfl_xor(sq,1);
        s += __shfl_xor(s,2); sq += __shfl_xor(sq,2);
        s += __shfl_xor(s,4); sq += __shfl_xor(sq,4);
        s += __shfl_xor(s,8); sq += __shfl_xor(sq,8);
        float mu = s*(1.f/128.f);
        float rstd = rsqrtf(sq*(1.f/128.f) - mu*mu + LN_EPS);
#pragma unroll
        for (int i = 0; i < 8; ++i){
            int cc = c0 + i;
            float h = (v[i]-mu)*rstd*aggr_g[cc] + aggr_be[cc];
            v[i] = fmaxf(h, 0.f);
        }
        *reinterpret_cast<float4*>(yr)     = *(float4*)&v[0];
        *reinterpret_cast<float4*>(yr + 4) = *(float4*)&v[4];
        uint4 pk = { pack2(v[0],v[1]), pack2(v[2],v[3]),
                     pack2(v[4],v[5]), pack2(v[6],v[7]) };
        *reinterpret_cast<uint4*>(&Sb[row*HD + SWZ(row, c0)]) = pk;
    }
    __syncthreads();

    // -------- y state into registers, MFMA D-layout --------
    f32x4 yA = *reinterpret_cast<const f32x4*>(preLN + rl*HD + c0e);
    f32x4 yB = *reinterpret_cast<const f32x4*>(preLN + (16+rl)*HD + c0e);
    __syncthreads();

    // -------- loop weights into registers (112 regs) --------
    bf16x8 WF1[4], WG1[4], WF2[4], WG2[4], WF3[4], WD1[4], WS1[4];
    loadW(wimg + 0*16384, lane, wid, WF1);
    loadW(wimg + 3*16384, lane, wid, WG1);
    loadW(wimg + 1*16384, lane, wid, WF2);
    loadW(wimg + 4*16384, lane, wid, WG2);
    loadW(wimg + 2*16384, lane, wid, WF3);
    loadW(wimg + 5*16384, lane, wid, WD1);
    loadW(wimg + 6*16384, lane, wid, WS1);

    // -------- loop-invariant per-channel params -> registers (12 x float4) --------
    const float4 cF0 = *(const float4*)(fb1 + c0e);
    const float4 cF1 = *(const float4*)(fw1 + 128*HD + c0e);
    const float4 cF2 = *(const float4*)(fw1 + 129*HD + c0e);
    const float4 cG0 = *(const float4*)(gb1 + c0e);
    const float4 cG1 = *(const float4*)(gw1 + 128*HD + c0e);
    const float4 cG2 = *(const float4*)(gw1 + 129*HD + c0e);
    const float4 cB6 = *(const float4*)(fb2 + c0e);
    const float4 cB7 = *(const float4*)(gb2 + c0e);
    const float4 cG3 = *(const float4*)(gw3 + c0e);
    const float4 cB8 = *(const float4*)(fb3 + c0e);
    const float4 cBD = *(const float4*)(db1 + c0e);
    const float4 cBS = *(const float4*)(sb1 + c0e);

    const float db20 = db2[0], db21 = db2[1];
    const float sb20 = sb2[0], sb21 = sb2[1];
    const float gb3v = gb3[0];
    float* wsB = wsOut + (size_t)bid*TSTEPS*128;

    f32x4 nzA, nzB;

    // -------- Euler-Maruyama scan: 3 barriers/step --------
    for (int k = 0; k <= TSTEPS; ++k) {
        const bool doL1 = (k < TSTEPS), doDS = (k >= 1);
        // PhA: noise prefetch (D-layout); L1f,L1g(t_k) and D1,S1 on Sb
        if (doL1) {
            const float* nb = noise + ((size_t)k*NROWS + r0)*HD;
            nzA = *reinterpret_cast<const f32x4*>(nb + (size_t)rl*HD + c0e);
            nzB = *reinterpret_cast<const f32x4*>(nb + (size_t)(16+rl)*HD + c0e);
        }
        {
            float4 bF, bG;
            if (doL1) {
                float t = k * DT_C;
                float st = __sinf(t), ct = __cosf(t);
                bF = make_float4(cF0.x + st*cF1.x + ct*cF2.x,
                                 cF0.y + st*cF1.y + ct*cF2.y,
                                 cF0.z + st*cF1.z + ct*cF2.z,
                                 cF0.w + st*cF1.w + ct*cF2.w);
                bG = make_float4(cG0.x + st*cG1.x + ct*cG2.x,
                                 cG0.y + st*cG1.y + ct*cG2.y,
                                 cG0.z + st*cG1.z + ct*cG2.z,
                                 cG0.w + st*cG1.w + ct*cG2.w);
            }
            if (doL1 && doDS) {
                f32x4 aF[2], aG[2], aD[2], aS[2];
                gemm4(Sb, WF1, WG1, WD1, WS1, lane, aF, aG, aD, aS);
                epiT(aF, bF, Ab, lane, wid);
                epiT(aG, bG, Bb, lane, wid);
                epiN(aD, cBD, Db, lane, wid);
                epiN(aS, cBS, Eb, lane, wid);
            } else if (doL1) {
                f32x4 aF[2], aG[2];
                gemm2(Sb, WF1, WG1, lane, aF, aG);
                epiT(aF, bF, Ab, lane, wid);
                epiT(aG, bG, Bb, lane, wid);
            } else {
                f32x4 aD[2], aS[2];
                gemm2(Sb, WD1, WS1, lane, aD, aS);
                epiN(aD, cBD, Db, lane, wid);
                epiN(aS, cBS, Eb, lane, wid);
            }
        }
        __syncthreads();
        // PhB: L2f(Ab->Cb); L2g(Bb->gpart, fused tanh+gw3); heads(k-1) LN part
        if (doL1) {
            f32x4 a1[2];
            gemm1(Ab, WF2, lane, a1);
            epiT(a1, cB6, Cb, lane, wid);
            gemm1(Bb, WG2, lane, a1);
            float p0 = tanh_f(a1[0][0]+cB7.x)*cG3.x + tanh_f(a1[0][1]+cB7.y)*cG3.y
                     + tanh_f(a1[0][2]+cB7.z)*cG3.z + tanh_f(a1[0][3]+cB7.w)*cG3.w;
            float p1 = tanh_f(a1[1][0]+cB7.x)*cG3.x + tanh_f(a1[1][1]+cB7.y)*cG3.y
                     + tanh_f(a1[1][2]+cB7.z)*cG3.z + tanh_f(a1[1][3]+cB7.w)*cG3.w;
            p0 += __shfl_xor(p0, 16); p0 += __shfl_xor(p0, 32);
            p1 += __shfl_xor(p1, 16); p1 += __shfl_xor(p1, 32);
            if ((lane >> 4) == 0) {
                gpart[rl*8 + wid]      = p0;
                gpart[(16+rl)*8 + wid] = p1;
            }
        }
        if (doDS) {
            float* dstStep = wsB + (size_t)(k-1)*128;
            if (tid < 256) head_ln(Db, ppd, db20, db21, 0, 0, tid, dstStep);
            else           head_ln(Eb, pps, sb20, sb21, 1, 2, tid-256, dstStep);
        }
        __syncthreads();
        // PhC: L3f(Cb) + gpart reduce + in-register Euler (D-layout) -> Sb
        if (doL1) {
            f32x4 a1[2];
            gemm1(Cb, WF3, lane, a1);
#pragma unroll
            for (int tr = 0; tr < 2; ++tr) {
                int r = tr*16 + rl;
                const float* gp = gpart + r*8;
                float4 u0 = *reinterpret_cast<const float4*>(gp);
                float4 u1 = *reinterpret_cast<const float4*>(gp + 4);
                float gs = u0.x+u0.y+u0.z+u0.w + u1.x+u1.y+u1.z+u1.w;
                float grow = sigm_f(gs + gb3v) * SQDT_C;
                f32x4& yy = (tr == 0) ? yA : yB;
                const f32x4& nz = (tr == 0) ? nzA : nzB;
                yy[0] += (a1[tr][0]+cB8.x)*DT_C + grow*nz[0];
                yy[1] += (a1[tr][1]+cB8.y)*DT_C + grow*nz[1];
                yy[2] += (a1[tr][2]+cB8.z)*DT_C + grow*nz[2];
                yy[3] += (a1[tr][3]+cB8.w)*DT_C + grow*nz[3];
                uint2 pk = { pack2(yy[0], yy[1]), pack2(yy[2], yy[3]) };
                *reinterpret_cast<uint2*>(Sb + r*HD + SWZ(r, c0e)) = pk;
            }
        }
        __syncthreads();
    }
}

extern "C" void kernel_launch(void* const* d_in, const int* in_sizes, int n_in,
                              void* d_out, int out_size, void* d_ws, size_t ws_size,
                              hipStream_t stream) {
    const float* lE      = (const float*)d_in[0];
    const float* gE      = (const float*)d_in[1];
    const float* noise   = (const float*)d_in[2];
    const float* aggr_w  = (const float*)d_in[3];
    const float* aggr_b  = (const float*)d_in[4];
    const float* aggr_g  = (const float*)d_in[5];
    const float* aggr_be = (const float*)d_in[6];
    const float* fw1 = (const float*)d_in[7];
    const float* fb1 = (const float*)d_in[8];
    const float* fw2 = (const float*)d_in[9];
    const float* fb2 = (const float*)d_in[10];
    const float* fw3 = (const float*)d_in[11];
    const float* fb3 = (const float*)d_in[12];
    const float* gw1 = (const float*)d_in[13];
    const float* gb1 = (const float*)d_in[14];
    const float* gw2 = (const float*)d_in[15];
    const float* gb2 = (const float*)d_in[16];
    const float* gw3 = (const float*)d_in[17];
    const float* gb3 = (const float*)d_in[18];
    const float* dw1 = (const float*)d_in[19];
    const float* db1 = (const float*)d_in[20];
    const float* dg  = (const float*)d_in[21];
    const float* dbe = (const float*)d_in[22];
    const float* dw2 = (const float*)d_in[23];
    const float* db2 = (const float*)d_in[24];
    const float* sw1 = (const float*)d_in[25];
    const float* sb1 = (const float*)d_in[26];
    const float* sg  = (const float*)d_in[27];
    const float* sbe = (const float*)d_in[28];
    const float* sw2 = (const float*)d_in[29];
    const float* sb2 = (const float*)d_in[30];
    const float* pw1 = (const float*)d_in[31];
    const float* pb1 = (const float*)d_in[32];
    const float* pg  = (const float*)d_in[33];
    const float* pbe = (const float*)d_in[34];
    const float* pw2 = (const float*)d_in[35];
    const float* pb2 = (const float*)d_in[36];
    const unsigned char* pmask = (const unsigned char*)d_in[37];
    float* outp = (float*)d_out;
    u16* wimg = (u16*)d_ws;                                  // 352 KB
    float* wsOut = (float*)((char*)d_ws + 360448);           // 768*3840 floats = 11.8 MB

    prep_w<<<dim3(64, 11), 256, 0, stream>>>(fw1, fw2, fw3, gw1, gw2, dw1, sw1,
                                             aggr_w, pw1, wimg);
    sde_fused<<<NBLKS, 512, 0, stream>>>(
        lE, gE, noise, aggr_b, aggr_g, aggr_be,
        fw1, fb1, fb2, fb3,
        gw1, gb1, gb2, gw3, gb3,
        db1, dg, dbe, dw2, db2,
        sb1, sg, sbe, sw2, sb2,
        pb1, pg, pbe, pw2, pb2,
        pmask, wimg, wsOut, outp);
    reorder_out<<<NBLKS, 256, 0, stream>>>(wsOut, outp);
}